// Round 2
// baseline (348.095 us; speedup 1.0000x reference)
//
#include <hip/hip_runtime.h>

typedef __attribute__((ext_vector_type(8))) short bf16x8;
typedef __attribute__((ext_vector_type(4))) float f32x4;

#define MFMA16(A,B,C) __builtin_amdgcn_mfma_f32_16x16x32_bf16(A,B,C,0,0,0)

__device__ __forceinline__ float bf2f(unsigned short h){
  unsigned int u = ((unsigned int)h) << 16;
  float f; __builtin_memcpy(&f,&u,4); return f;
}
__device__ __forceinline__ unsigned short f2bf(float f){
  unsigned int u; __builtin_memcpy(&u,&f,4);
  unsigned int r = (u + 0x7fffu + ((u>>16)&1u)) >> 16;   // RNE
  return (unsigned short)r;
}

// fp32 -> bf16 (RNE), 8 elements/thread. n must be multiple of 2048.
__global__ __launch_bounds__(256) void cast_bf16(const float* __restrict__ src,
                                                 unsigned short* __restrict__ dst)
{
  int i = blockIdx.x*256 + threadIdx.x;
  float4 a = reinterpret_cast<const float4*>(src)[2*i];
  float4 b = reinterpret_cast<const float4*>(src)[2*i+1];
  unsigned short tmp[8] = {f2bf(a.x),f2bf(a.y),f2bf(a.z),f2bf(a.w),
                           f2bf(b.x),f2bf(b.y),f2bf(b.z),f2bf(b.w)};
  reinterpret_cast<uint4*>(dst)[i] = *reinterpret_cast<const uint4*>(tmp);
}

// C[M,N] = A[M,K] @ W[N,K]^T + bias[N]; A,W bf16, fp32 acc, bias fp32.
// OUT_MODE 0: fp32 row-major [M,N].  OUT_MODE 1: bf16 head layout [(b*16+h)*2048+s]*64+d.
template<int OUT_MODE>
__global__ __launch_bounds__(256) void gemm_bt(const unsigned short* __restrict__ A,
                                               const unsigned short* __restrict__ W,
                                               const float* __restrict__ bias,
                                               void* __restrict__ Cv,
                                               int M, int N, int K)
{
  __shared__ __align__(16) unsigned short lds_a[128*40];  // 128 rows x 32 (+8 pad)
  __shared__ __align__(16) unsigned short lds_w[128*40];
  const int t = threadIdx.x;
  const int lane = t & 63, wave = t >> 6;
  const int wm = wave >> 1, wn = wave & 1;
  const int lr = lane & 15, quad = lane >> 4;
  const int n0 = blockIdx.x * 128, m0 = blockIdx.y * 128;

  const f32x4 fzero = {0.f,0.f,0.f,0.f};
  f32x4 acc[4][4];
  #pragma unroll
  for (int i=0;i<4;++i)
    #pragma unroll
    for (int j=0;j<4;++j) acc[i][j] = fzero;

  for (int k0 = 0; k0 < K; k0 += 32) {
    __syncthreads();
    #pragma unroll
    for (int it=0; it<2; ++it) {
      int c = t + it*256;                // 512 chunks of 8 bf16
      int row = c >> 2, col = (c & 3) * 8;
      *reinterpret_cast<uint4*>(&lds_a[row*40 + col]) =
        *reinterpret_cast<const uint4*>(&A[(size_t)(m0+row)*K + k0 + col]);
      *reinterpret_cast<uint4*>(&lds_w[row*40 + col]) =
        *reinterpret_cast<const uint4*>(&W[(size_t)(n0+row)*K + k0 + col]);
    }
    __syncthreads();
    bf16x8 af[4], bfr[4];
    #pragma unroll
    for (int mt=0; mt<4; ++mt)
      af[mt] = *reinterpret_cast<const bf16x8*>(&lds_a[(wm*64 + mt*16 + lr)*40 + quad*8]);
    #pragma unroll
    for (int nt=0; nt<4; ++nt)
      bfr[nt] = *reinterpret_cast<const bf16x8*>(&lds_w[(wn*64 + nt*16 + lr)*40 + quad*8]);
    #pragma unroll
    for (int mt=0; mt<4; ++mt)
      #pragma unroll
      for (int nt=0; nt<4; ++nt)
        acc[mt][nt] = MFMA16(af[mt], bfr[nt], acc[mt][nt]);
  }

  #pragma unroll
  for (int nt=0; nt<4; ++nt) {
    int n = n0 + wn*64 + nt*16 + lr;
    float bv = bias[n];
    #pragma unroll
    for (int mt=0; mt<4; ++mt) {
      #pragma unroll
      for (int r=0; r<4; ++r) {
        int m = m0 + wm*64 + mt*16 + quad*4 + r;
        float v = acc[mt][nt][r] + bv;
        if (OUT_MODE == 0) {
          reinterpret_cast<float*>(Cv)[(size_t)m * N + n] = v;
        } else {
          int b = m >> 11, s = m & 2047, hh = n >> 6, d = n & 63;
          reinterpret_cast<unsigned short*>(Cv)[((size_t)(b*16 + hh) * 2048 + s) * 64 + d] = f2bf(v);
        }
      }
    }
  }
}

// In-place RMSNorm (over H=1024, pre-head-split channels) + RoPE, on [B,H,S,D] bf16.
__global__ __launch_bounds__(256) void rmsrope(unsigned short* __restrict__ buf,
                                               const float* __restrict__ cosb,
                                               const float* __restrict__ sinb,
                                               const float* __restrict__ w)
{
  const int bs = blockIdx.x;
  const int b = bs >> 11, s = bs & 2047;
  const int t = threadIdx.x;
  float x1[2], x2[2];
  float ss = 0.f;
  #pragma unroll
  for (int i=0;i<2;++i){
    int p = t + i*256;            // pair id: 512 pairs cover all 1024 channels
    int h = p >> 5, d = p & 31;
    size_t base = ((size_t)(b*16+h)*2048 + s)*64;
    x1[i] = bf2f(buf[base + d]);
    x2[i] = bf2f(buf[base + d + 32]);
    ss += x1[i]*x1[i] + x2[i]*x2[i];
  }
  #pragma unroll
  for (int off=32; off>0; off>>=1) ss += __shfl_xor(ss, off, 64);
  __shared__ float red[4];
  if ((t & 63) == 0) red[t>>6] = ss;
  __syncthreads();
  float tot = red[0]+red[1]+red[2]+red[3];
  float r = rsqrtf(tot * (1.0f/1024.0f) + 1e-6f);
  #pragma unroll
  for (int i=0;i<2;++i){
    int p = t + i*256;
    int h = p >> 5, d = p & 31;
    size_t base = ((size_t)(b*16+h)*2048 + s)*64;
    float w1 = w[h*64+d], w2 = w[h*64+d+32];
    float n1 = x1[i]*r*w1, n2 = x2[i]*r*w2;
    float c1 = cosb[s*64+d],    s1 = sinb[s*64+d];
    float c2 = cosb[s*64+d+32], s2 = sinb[s*64+d+32];
    buf[base+d]    = f2bf(n1*c1 - n2*s1);   // q*c + rotate_half(q)*s, first half
    buf[base+d+32] = f2bf(n2*c2 + n1*s2);   // second half
  }
}

// Flash-style attention. Block = (b,h, 64 q-rows). Wave w owns q-rows [w*16, w*16+16).
// scores = QK^T/8 + (k<=q ? 1 : 0); softmax over all keys (bounded scores -> no max-tracking).
__global__ __launch_bounds__(256) void attn(const unsigned short* __restrict__ qh,
                                            const unsigned short* __restrict__ kh,
                                            const unsigned short* __restrict__ vh,
                                            unsigned short* __restrict__ ao)
{
  __shared__ __align__(16) unsigned short kbuf[64*72];    // [key][d], pad 72
  __shared__ __align__(16) unsigned short vbuf[64*72];    // [d][key] (V^T), pad 72
  __shared__ __align__(16) unsigned short pbuf[4*16*72];  // per-wave P [q][key]
  const int t = threadIdx.x;
  const int lane = t & 63, w = t >> 6;
  const int lr = lane & 15, quad = lane >> 4;
  const int qbase = blockIdx.x * 64;
  const int bh = blockIdx.y;
  const int b = bh >> 4, h = bh & 15;
  const size_t hb = (size_t)bh * 2048 * 64;
  const unsigned short* qp = qh + hb;
  const unsigned short* kp = kh + hb;
  const unsigned short* vp = vh + hb;

  const int qrow_a = qbase + w*16 + lr;                 // A-fragment row
  bf16x8 qf0 = *reinterpret_cast<const bf16x8*>(&qp[(size_t)qrow_a*64 + quad*8]);
  bf16x8 qf1 = *reinterpret_cast<const bf16x8*>(&qp[(size_t)qrow_a*64 + 32 + quad*8]);

  const f32x4 fzero = {0.f,0.f,0.f,0.f};
  f32x4 oacc[4];
  #pragma unroll
  for (int i=0;i<4;++i) oacc[i] = fzero;
  float lsum[4] = {0.f,0.f,0.f,0.f};
  const int qrow_c = qbase + w*16 + quad*4;             // C-layout row (+r)
  unsigned short* pw = &pbuf[w*16*72];

  for (int kt=0; kt<32; ++kt) {
    __syncthreads();   // protect kbuf/vbuf against previous iteration's readers
    #pragma unroll
    for (int it=0; it<2; ++it) {
      int c = t + it*256;
      int row = c >> 3, cg = (c & 7) * 8;
      *reinterpret_cast<uint4*>(&kbuf[row*72 + cg]) =
        *reinterpret_cast<const uint4*>(&kp[(size_t)(kt*64+row)*64 + cg]);
      unsigned short tmp[8];
      *reinterpret_cast<uint4*>(tmp) =
        *reinterpret_cast<const uint4*>(&vp[(size_t)(kt*64+row)*64 + cg]);
      #pragma unroll
      for (int j=0;j<8;++j) vbuf[(cg+j)*72 + row] = tmp[j];   // transpose into LDS
    }
    __syncthreads();

    // S = Q @ K_tile^T, then P = exp(S/8 + mask), C-layout -> LDS (A-layout source)
    #pragma unroll
    for (int nt=0; nt<4; ++nt) {
      bf16x8 b0 = *reinterpret_cast<const bf16x8*>(&kbuf[(nt*16+lr)*72 + quad*8]);
      bf16x8 b1 = *reinterpret_cast<const bf16x8*>(&kbuf[(nt*16+lr)*72 + 32 + quad*8]);
      f32x4 z = fzero;
      z = MFMA16(qf0, b0, z);
      z = MFMA16(qf1, b1, z);
      int key0 = kt*64 + nt*16 + lr;
      #pragma unroll
      for (int r=0; r<4; ++r) {
        float sc = z[r]*0.125f + ((key0 <= qrow_c + r) ? 1.0f : 0.0f);
        float p = __expf(sc);
        lsum[r] += p;
        pw[(quad*4+r)*72 + nt*16 + lr] = f2bf(p);
      }
    }
    __syncthreads();

    // O += P @ V_tile
    bf16x8 pf0 = *reinterpret_cast<const bf16x8*>(&pw[lr*72 + quad*8]);
    bf16x8 pf1 = *reinterpret_cast<const bf16x8*>(&pw[lr*72 + 32 + quad*8]);
    #pragma unroll
    for (int nt=0; nt<4; ++nt) {
      bf16x8 v0 = *reinterpret_cast<const bf16x8*>(&vbuf[(nt*16+lr)*72 + quad*8]);
      bf16x8 v1 = *reinterpret_cast<const bf16x8*>(&vbuf[(nt*16+lr)*72 + 32 + quad*8]);
      oacc[nt] = MFMA16(pf0, v0, oacc[nt]);
      oacc[nt] = MFMA16(pf1, v1, oacc[nt]);
    }
  }

  // row-sum across the 16 lanes of each quad (keys), then normalize + store (bf16 [B*S,H])
  #pragma unroll
  for (int r=0; r<4; ++r) {
    #pragma unroll
    for (int off=1; off<16; off<<=1) lsum[r] += __shfl_xor(lsum[r], off, 64);
  }
  #pragma unroll
  for (int r=0; r<4; ++r) {
    float inv = 1.0f / lsum[r];
    int qrow = qrow_c + r;
    size_t rowbase = ((size_t)(b*2048 + qrow))*1024 + h*64;
    #pragma unroll
    for (int nt=0; nt<4; ++nt)
      ao[rowbase + nt*16 + lr] = f2bf(oacc[nt][r] * inv);
  }
}

extern "C" void kernel_launch(void* const* d_in, const int* in_sizes, int n_in,
                              void* d_out, int out_size, void* d_ws, size_t ws_size,
                              hipStream_t stream)
{
  const float* hs   = (const float*)d_in[0];
  const float* cosb = (const float*)d_in[1];
  const float* sinb = (const float*)d_in[2];
  const float* Wq   = (const float*)d_in[3];
  const float* bq   = (const float*)d_in[4];
  const float* Wk   = (const float*)d_in[5];
  const float* bk   = (const float*)d_in[6];
  const float* Wv   = (const float*)d_in[7];
  const float* bv   = (const float*)d_in[8];
  const float* Wo   = (const float*)d_in[9];
  const float* bo   = (const float*)d_in[10];
  const float* rw   = (const float*)d_in[11];

  const size_t NEL = (size_t)4096 * 1024;   // 4M elements
  const size_t WEL = (size_t)1024 * 1024;   // 1M elements
  unsigned short* hsb = (unsigned short*)d_ws;     // bf16 copies
  unsigned short* wqb = hsb + NEL;
  unsigned short* wkb = wqb + WEL;
  unsigned short* wvb = wkb + WEL;
  unsigned short* wob = wvb + WEL;
  unsigned short* qhb = wob + WEL;                 // [B,H,S,D] bf16
  unsigned short* khb = qhb + NEL;
  unsigned short* vhb = khb + NEL;
  unsigned short* aob = vhb + NEL;                 // [B*S, H] bf16

  cast_bf16<<<2048, 256, 0, stream>>>(hs, hsb);
  cast_bf16<<< 512, 256, 0, stream>>>(Wq, wqb);
  cast_bf16<<< 512, 256, 0, stream>>>(Wk, wkb);
  cast_bf16<<< 512, 256, 0, stream>>>(Wv, wvb);
  cast_bf16<<< 512, 256, 0, stream>>>(Wo, wob);

  dim3 gg(8, 32);
  gemm_bt<1><<<gg, 256, 0, stream>>>(hsb, wqb, bq, qhb, 4096, 1024, 1024);
  gemm_bt<1><<<gg, 256, 0, stream>>>(hsb, wkb, bk, khb, 4096, 1024, 1024);
  gemm_bt<1><<<gg, 256, 0, stream>>>(hsb, wvb, bv, vhb, 4096, 1024, 1024);
  rmsrope<<<4096, 256, 0, stream>>>(qhb, cosb, sinb, rw);
  rmsrope<<<4096, 256, 0, stream>>>(khb, cosb, sinb, rw);
  attn<<<dim3(32, 32), 256, 0, stream>>>(qhb, khb, vhb, aob);
  gemm_bt<0><<<gg, 256, 0, stream>>>(aob, wob, bo, d_out, 4096, 1024, 1024);
}

// Round 5
// 253.408 us; speedup vs baseline: 1.3737x; 1.3737x over previous
//
#include <hip/hip_runtime.h>

typedef unsigned short u16;
typedef __attribute__((ext_vector_type(8))) short bf16x8;
typedef __attribute__((ext_vector_type(4))) float f32x4;

#define MFMA16(A,B,C) __builtin_amdgcn_mfma_f32_16x16x32_bf16(A,B,C,0,0,0)

__device__ __forceinline__ u16 f2bf(float f){
  unsigned int u; __builtin_memcpy(&u,&f,4);
  unsigned int r = (u + 0x7fffu + ((u>>16)&1u)) >> 16;   // RNE
  return (u16)r;
}
__device__ __forceinline__ float bf2f(u16 h){
  unsigned int u = ((unsigned int)h) << 16;
  float f; __builtin_memcpy(&f,&u,4); return f;
}

// async global->LDS, 16B per lane; LDS dest = wave-uniform base + lane*16.
__device__ __forceinline__ void async_ld16(const void* g, void* l) {
  __builtin_amdgcn_global_load_lds(
      (const __attribute__((address_space(1))) unsigned int*)g,
      (__attribute__((address_space(3))) unsigned int*)l, 16, 0, 0);
}

// Cast hs (4M el) + Wq,Wk,Wv,Wo (1M each) fp32->bf16 into contiguous ws.
__global__ __launch_bounds__(256) void cast_all(const float* __restrict__ hs,
    const float* __restrict__ wq, const float* __restrict__ wk,
    const float* __restrict__ wv, const float* __restrict__ wo,
    u16* __restrict__ dst)
{
  unsigned int i = blockIdx.x*256 + threadIdx.x;     // chunk of 8 elements
  size_t el = (size_t)i * 8;
  const float* src; size_t off;
  if (el < 4194304) { src = hs; off = el; }
  else {
    unsigned int r = (unsigned int)((el - 4194304) >> 20);
    src = (r==0)?wq:(r==1)?wk:(r==2)?wv:wo;
    off = (el - 4194304) & 1048575;
  }
  float4 a = *reinterpret_cast<const float4*>(src+off);
  float4 b = *reinterpret_cast<const float4*>(src+off+4);
  u16 tmp[8] = {f2bf(a.x),f2bf(a.y),f2bf(a.z),f2bf(a.w),
                f2bf(b.x),f2bf(b.y),f2bf(b.z),f2bf(b.w)};
  *reinterpret_cast<uint4*>(dst + el) = *reinterpret_cast<const uint4*>(tmp);
}

// C = A[M,K] @ W[N,K]^T + bias. m97 structure: global_load_lds staging, unpadded LDS.
// MODE 0: fp32 out [M,N], bias=b0p.  MODE 1: bf16 qkv-routed head layout, which=n/1024.
template<int MODE>
__global__ __launch_bounds__(256) void gemm_k(const u16* __restrict__ A,
                                              const u16* __restrict__ W,
                                              const float* __restrict__ b0p,
                                              const float* __restrict__ b1p,
                                              const float* __restrict__ b2p,
                                              void* __restrict__ out,
                                              int M, int N, int K)
{
  __shared__ __align__(16) u16 lds_a[128*32];
  __shared__ __align__(16) u16 lds_w[128*32];
  const int t = threadIdx.x;
  const int lane = t & 63, wave = t >> 6;
  const int wm = wave >> 1, wn = wave & 1;
  const int lr = lane & 15, quad = lane >> 4;
  const int n0 = blockIdx.x * 128, m0 = blockIdx.y * 128;
  const int wbase = t & 192;                 // wave*64, wave-uniform

  const f32x4 fzero = {0.f,0.f,0.f,0.f};
  f32x4 acc[4][4];
  #pragma unroll
  for (int i=0;i<4;++i)
    #pragma unroll
    for (int j=0;j<4;++j) acc[i][j] = fzero;

  for (int k0 = 0; k0 < K; k0 += 32) {
    __syncthreads();
    #pragma unroll
    for (int it=0; it<2; ++it) {
      int idx = it*256 + t;                  // 512 chunks of 16B per tile
      int row = idx >> 2, c8 = (idx & 3) * 8;
      int lbase = (it*256 + wbase) * 8;      // wave-uniform LDS element base
      async_ld16(&A[(size_t)(m0+row)*K + k0 + c8], &lds_a[lbase]);
      async_ld16(&W[(size_t)(n0+row)*K + k0 + c8], &lds_w[lbase]);
    }
    __syncthreads();
    bf16x8 af[4], bfr[4];
    #pragma unroll
    for (int mt=0; mt<4; ++mt)
      af[mt] = *reinterpret_cast<const bf16x8*>(&lds_a[(wm*64 + mt*16 + lr)*32 + quad*8]);
    #pragma unroll
    for (int nt=0; nt<4; ++nt)
      bfr[nt] = *reinterpret_cast<const bf16x8*>(&lds_w[(wn*64 + nt*16 + lr)*32 + quad*8]);
    #pragma unroll
    for (int mt=0; mt<4; ++mt)
      #pragma unroll
      for (int nt=0; nt<4; ++nt)
        acc[mt][nt] = MFMA16(af[mt], bfr[nt], acc[mt][nt]);
  }

  if (MODE == 0) {
    float* O = reinterpret_cast<float*>(out);
    #pragma unroll
    for (int nt=0; nt<4; ++nt) {
      int n = n0 + wn*64 + nt*16 + lr;
      float bv = b0p[n];
      #pragma unroll
      for (int mt=0; mt<4; ++mt)
        #pragma unroll
        for (int r=0; r<4; ++r) {
          int m = m0 + wm*64 + mt*16 + quad*4 + r;
          O[(size_t)m * N + n] = acc[mt][nt][r] + bv;
        }
    }
  } else {
    int which = n0 >> 10;                    // block-uniform (128 | 1024)
    const float* bp = (which==0) ? b0p : (which==1) ? b1p : b2p;
    u16* dst = reinterpret_cast<u16*>(out) + (size_t)which * 4194304;
    #pragma unroll
    for (int nt=0; nt<4; ++nt) {
      int nn = (n0 & 1023) + wn*64 + nt*16 + lr;
      float bv = bp[nn];
      int hh = nn >> 6, d = nn & 63;
      #pragma unroll
      for (int mt=0; mt<4; ++mt)
        #pragma unroll
        for (int r=0; r<4; ++r) {
          int m = m0 + wm*64 + mt*16 + quad*4 + r;
          int b = m >> 11, s = m & 2047;
          dst[((size_t)(b*16 + hh) * 2048 + s) * 64 + d] = f2bf(acc[mt][nt][r] + bv);
        }
    }
  }
}

// In-place RMSNorm (over the 1024 pre-split channels) + RoPE on [B,H,S,D] bf16.
// blockIdx.y selects q (0) or k (1).
__global__ __launch_bounds__(256) void rmsrope(u16* __restrict__ qb, u16* __restrict__ kb,
                                               const float* __restrict__ cosb,
                                               const float* __restrict__ sinb,
                                               const float* __restrict__ w)
{
  u16* buf = blockIdx.y ? kb : qb;
  const int bs = blockIdx.x;
  const int b = bs >> 11, s = bs & 2047;
  const int t = threadIdx.x;
  float x1[2], x2[2];
  float ss = 0.f;
  #pragma unroll
  for (int i=0;i<2;++i){
    int p = t + i*256;            // 512 pairs cover 1024 channels
    int h = p >> 5, d = p & 31;
    size_t base = ((size_t)(b*16+h)*2048 + s)*64;
    x1[i] = bf2f(buf[base + d]);
    x2[i] = bf2f(buf[base + d + 32]);
    ss += x1[i]*x1[i] + x2[i]*x2[i];
  }
  #pragma unroll
  for (int off=32; off>0; off>>=1) ss += __shfl_xor(ss, off, 64);
  __shared__ float red[4];
  if ((t & 63) == 0) red[t>>6] = ss;
  __syncthreads();
  float tot = red[0]+red[1]+red[2]+red[3];
  float r = rsqrtf(tot * (1.0f/1024.0f) + 1e-6f);
  #pragma unroll
  for (int i=0;i<2;++i){
    int p = t + i*256;
    int h = p >> 5, d = p & 31;
    size_t base = ((size_t)(b*16+h)*2048 + s)*64;
    float w1 = w[h*64+d], w2 = w[h*64+d+32];
    float n1 = x1[i]*r*w1, n2 = x2[i]*r*w2;
    float c1 = cosb[s*64+d],    s1 = sinb[s*64+d];
    float c2 = cosb[s*64+d+32], s2 = sinb[s*64+d+32];
    buf[base+d]    = f2bf(n1*c1 - n2*s1);
    buf[base+d+32] = f2bf(n2*c2 + n1*s2);
  }
}

// V [bh][s][d] -> V^T [bh][d][s], 64x64 tiles, XOR-swizzled LDS (2-way max).
__global__ __launch_bounds__(256) void vtrans(const u16* __restrict__ v, u16* __restrict__ vt)
{
  __shared__ __align__(16) u16 tile[64*72];
  const int t = threadIdx.x;
  const int sb = blockIdx.x, bh = blockIdx.y;
  const u16* vp = v + (size_t)bh*2048*64 + (size_t)sb*64*64;
  #pragma unroll
  for (int it=0; it<2; ++it) {
    int idx = it*256 + t;
    int srow = idx >> 3, dch = idx & 7;
    uint4 val = *reinterpret_cast<const uint4*>(&vp[(size_t)srow*64 + dch*8]);
    *reinterpret_cast<uint4*>(&tile[srow*72 + ((dch ^ (srow>>3))&7)*8]) = val;
  }
  __syncthreads();
  u16* op = vt + (size_t)bh*64*2048 + sb*64;
  #pragma unroll
  for (int it=0; it<2; ++it) {
    int idx = it*256 + t;
    int drow = idx >> 3, sch = idx & 7;
    u16 tmp[8];
    #pragma unroll
    for (int i=0;i<8;++i) {
      int srow = sch*8 + i;
      tmp[i] = tile[srow*72 + (((drow>>3) ^ sch)&7)*8 + (drow&7)];
    }
    *reinterpret_cast<uint4*>(&op[(size_t)drow*2048 + sch*8]) = *reinterpret_cast<const uint4*>(tmp);
  }
}

// Flash attention. Block = (64 q-rows, b*16+h). Explicit staging: uint4 global load ->
// XOR-chunk-swizzled ds_write_b128 (unpadded LDS, conflict-free b128 fragment reads).
__global__ __launch_bounds__(256) void attn(const u16* __restrict__ qh,
                                            const u16* __restrict__ kh,
                                            const u16* __restrict__ vt,
                                            u16* __restrict__ ao)
{
  __shared__ __align__(16) u16 kbuf[64*64];     // [key][d], chunk pos = c ^ (key&7)
  __shared__ __align__(16) u16 vbuf[64*64];     // [d][key], chunk pos = c ^ (d&7)
  __shared__ __align__(16) u16 pbuf[4*16*72];   // per-wave P [q][key]
  const int t = threadIdx.x;
  const int lane = t & 63, w = t >> 6;
  const int lr = lane & 15, quad = lane >> 4;
  const int qbase = blockIdx.x * 64;
  const int bh = blockIdx.y;
  const int b = bh >> 4, h = bh & 15;
  const size_t hb = (size_t)bh * 2048 * 64;
  const u16* qp = qh + hb;
  const u16* kp = kh + hb;
  const u16* vtp = vt + hb;

  const int qrow_a = qbase + w*16 + lr;
  bf16x8 qf0 = *reinterpret_cast<const bf16x8*>(&qp[(size_t)qrow_a*64 + quad*8]);
  bf16x8 qf1 = *reinterpret_cast<const bf16x8*>(&qp[(size_t)qrow_a*64 + 32 + quad*8]);

  const f32x4 fzero = {0.f,0.f,0.f,0.f};
  f32x4 oacc[4];
  #pragma unroll
  for (int i=0;i<4;++i) oacc[i] = fzero;
  float lsum[4] = {0.f,0.f,0.f,0.f};
  const int qrow_c = qbase + w*16 + quad*4;
  u16* pw = &pbuf[w*16*72];
  const int fr = lr >> 2;                       // pbuf read swizzle

  for (int kt=0; kt<32; ++kt) {
    __syncthreads();                            // kbuf/vbuf free (prev readers done)
    #pragma unroll
    for (int it=0; it<2; ++it) {
      int idx = it*256 + t;
      int row = idx >> 3, c = idx & 7;          // row: key (kbuf) / d (vbuf)
      uint4 kvv = *reinterpret_cast<const uint4*>(&kp[(size_t)(kt*64+row)*64 + c*8]);
      uint4 vvv = *reinterpret_cast<const uint4*>(&vtp[(size_t)row*2048 + kt*64 + c*8]);
      int sw = ((c ^ (row&7))&7)*8;
      *reinterpret_cast<uint4*>(&kbuf[row*64 + sw]) = kvv;
      *reinterpret_cast<uint4*>(&vbuf[row*64 + sw]) = vvv;
    }
    __syncthreads();

    // S = Q K^T ; P = exp(S/8 + causal+1) ; write P to wave-private pbuf
    #pragma unroll
    for (int nt=0; nt<4; ++nt) {
      int row = nt*16 + lr, sw = row & 7;
      bf16x8 b0 = *reinterpret_cast<const bf16x8*>(&kbuf[row*64 + ((quad ^ sw)&7)*8]);
      bf16x8 b1 = *reinterpret_cast<const bf16x8*>(&kbuf[row*64 + ((quad ^ sw ^ 4)&7)*8]);
      f32x4 z = fzero;
      z = MFMA16(qf0, b0, z);
      z = MFMA16(qf1, b1, z);
      int key0 = kt*64 + nt*16 + lr;
      #pragma unroll
      for (int r=0; r<4; ++r) {
        float sc = z[r]*0.125f + ((key0 <= qrow_c + r) ? 1.0f : 0.0f);
        float p = __expf(sc);
        lsum[r] += p;
        int qr = quad*4 + r;
        pw[qr*72 + (((nt*2 + (lr>>3)) ^ quad)<<3) + (lr&7)] = f2bf(p);
      }
    }
    // no barrier: pbuf is wave-private; same-wave LDS ops complete in order

    bf16x8 pf0 = *reinterpret_cast<const bf16x8*>(&pw[lr*72 + ((quad ^ fr)&7)*8]);
    bf16x8 pf1 = *reinterpret_cast<const bf16x8*>(&pw[lr*72 + ((quad ^ fr ^ 4)&7)*8]);
    #pragma unroll
    for (int nt=0; nt<4; ++nt) {
      int d = nt*16 + lr, sw = d & 7;
      bf16x8 v0 = *reinterpret_cast<const bf16x8*>(&vbuf[d*64 + ((quad ^ sw)&7)*8]);
      bf16x8 v1 = *reinterpret_cast<const bf16x8*>(&vbuf[d*64 + ((quad ^ sw ^ 4)&7)*8]);
      oacc[nt] = MFMA16(pf0, v0, oacc[nt]);
      oacc[nt] = MFMA16(pf1, v1, oacc[nt]);
    }
  }

  #pragma unroll
  for (int r=0; r<4; ++r) {
    #pragma unroll
    for (int off=1; off<16; off<<=1) lsum[r] += __shfl_xor(lsum[r], off, 64);
  }
  #pragma unroll
  for (int r=0; r<4; ++r) {
    float inv = 1.0f / lsum[r];
    int qrow = qrow_c + r;
    size_t rowbase = ((size_t)(b*2048 + qrow))*1024 + h*64;
    #pragma unroll
    for (int nt=0; nt<4; ++nt)
      ao[rowbase + nt*16 + lr] = f2bf(oacc[nt][r] * inv);
  }
}

extern "C" void kernel_launch(void* const* d_in, const int* in_sizes, int n_in,
                              void* d_out, int out_size, void* d_ws, size_t ws_size,
                              hipStream_t stream)
{
  const float* hs   = (const float*)d_in[0];
  const float* cosb = (const float*)d_in[1];
  const float* sinb = (const float*)d_in[2];
  const float* Wq   = (const float*)d_in[3];
  const float* bq   = (const float*)d_in[4];
  const float* Wk   = (const float*)d_in[5];
  const float* bk   = (const float*)d_in[6];
  const float* Wv   = (const float*)d_in[7];
  const float* bv   = (const float*)d_in[8];
  const float* Wo   = (const float*)d_in[9];
  const float* bo   = (const float*)d_in[10];
  const float* rw   = (const float*)d_in[11];

  const size_t NEL = (size_t)4096 * 1024;   // 4M
  const size_t WEL = (size_t)1024 * 1024;   // 1M
  u16* hsb = (u16*)d_ws;                    // bf16 hs [4096,1024]
  u16* wqb = hsb + NEL;                     // Wq,Wk,Wv contiguous (fused QKV GEMM)
  u16* wob = wqb + 3*WEL;
  u16* qhb = wob + WEL;                     // q,k,v head layout [B,H,S,D], contiguous
  u16* khb = qhb + NEL;
  u16* vhb = khb + NEL;
  u16* vtb = vhb + NEL;                     // V^T [B,H,D,S]
  u16* aob = hsb;                           // reuse: hs consumed by QKV GEMM

  cast_all<<<4096, 256, 0, stream>>>(hs, Wq, Wk, Wv, Wo, hsb);
  gemm_k<1><<<dim3(24,32), 256, 0, stream>>>(hsb, wqb, bq, bk, bv, qhb, 4096, 3072, 1024);
  rmsrope<<<dim3(4096,2), 256, 0, stream>>>(qhb, khb, cosb, sinb, rw);
  vtrans<<<dim3(32,32), 256, 0, stream>>>(vhb, vtb);
  attn<<<dim3(32,32), 256, 0, stream>>>(qhb, khb, vtb, aob);
  gemm_k<0><<<dim3(8,32), 256, 0, stream>>>(aob, wob, bo, nullptr, nullptr, d_out, 4096, 1024, 1024);
}

// Round 6
// 250.043 us; speedup vs baseline: 1.3921x; 1.0135x over previous
//
#include <hip/hip_runtime.h>

typedef unsigned short u16;
typedef __attribute__((ext_vector_type(8))) short bf16x8;
typedef __attribute__((ext_vector_type(4))) short bf16x4;
typedef __attribute__((ext_vector_type(4))) float f32x4;

#define MFMA16(A,B,C) __builtin_amdgcn_mfma_f32_16x16x32_bf16(A,B,C,0,0,0)

__device__ __forceinline__ u16 f2bf(float f){
  unsigned int u; __builtin_memcpy(&u,&f,4);
  unsigned int r = (u + 0x7fffu + ((u>>16)&1u)) >> 16;   // RNE
  return (u16)r;
}
__device__ __forceinline__ float bf2f(u16 h){
  unsigned int u = ((unsigned int)h) << 16;
  float f; __builtin_memcpy(&f,&u,4); return f;
}

// async global->LDS, 16B per lane; LDS dest = wave-uniform base + lane*16.
__device__ __forceinline__ void async_ld16(const void* g, void* l) {
  __builtin_amdgcn_global_load_lds(
      (const __attribute__((address_space(1))) unsigned int*)g,
      (__attribute__((address_space(3))) unsigned int*)l, 16, 0, 0);
}

// Cast hs (4M el) + Wq,Wk,Wv,Wo (1M each) fp32->bf16 into contiguous ws.
__global__ __launch_bounds__(256) void cast_all(const float* __restrict__ hs,
    const float* __restrict__ wq, const float* __restrict__ wk,
    const float* __restrict__ wv, const float* __restrict__ wo,
    u16* __restrict__ dst)
{
  unsigned int i = blockIdx.x*256 + threadIdx.x;     // chunk of 8 elements
  size_t el = (size_t)i * 8;
  const float* src; size_t off;
  if (el < 4194304) { src = hs; off = el; }
  else {
    unsigned int r = (unsigned int)((el - 4194304) >> 20);
    src = (r==0)?wq:(r==1)?wk:(r==2)?wv:wo;
    off = (el - 4194304) & 1048575;
  }
  float4 a = *reinterpret_cast<const float4*>(src+off);
  float4 b = *reinterpret_cast<const float4*>(src+off+4);
  u16 tmp[8] = {f2bf(a.x),f2bf(a.y),f2bf(a.z),f2bf(a.w),
                f2bf(b.x),f2bf(b.y),f2bf(b.z),f2bf(b.w)};
  *reinterpret_cast<uint4*>(dst + el) = *reinterpret_cast<const uint4*>(tmp);
}

// C = A[M,K] @ W[N,K]^T + bias. m97 structure: global_load_lds staging, unpadded LDS.
// MODE 0: fp32 out [M,N], bias=b0p.
// MODE 1: bf16; which = n/1024 routes to q/k head layout [bh][s][d]; v (which==2)
//         is written TRANSPOSED [bh][d][s] with packed b64 stores (feeds attn directly).
template<int MODE>
__global__ __launch_bounds__(256) void gemm_k(const u16* __restrict__ A,
                                              const u16* __restrict__ W,
                                              const float* __restrict__ b0p,
                                              const float* __restrict__ b1p,
                                              const float* __restrict__ b2p,
                                              void* __restrict__ out,
                                              int M, int N, int K)
{
  __shared__ __align__(16) u16 lds_a[128*32];
  __shared__ __align__(16) u16 lds_w[128*32];
  const int t = threadIdx.x;
  const int lane = t & 63, wave = t >> 6;
  const int wm = wave >> 1, wn = wave & 1;
  const int lr = lane & 15, quad = lane >> 4;
  const int n0 = blockIdx.x * 128, m0 = blockIdx.y * 128;
  const int wbase = t & 192;                 // wave*64, wave-uniform

  const f32x4 fzero = {0.f,0.f,0.f,0.f};
  f32x4 acc[4][4];
  #pragma unroll
  for (int i=0;i<4;++i)
    #pragma unroll
    for (int j=0;j<4;++j) acc[i][j] = fzero;

  for (int k0 = 0; k0 < K; k0 += 32) {
    __syncthreads();
    #pragma unroll
    for (int it=0; it<2; ++it) {
      int idx = it*256 + t;                  // 512 chunks of 16B per tile
      int row = idx >> 2, c8 = (idx & 3) * 8;
      int lbase = (it*256 + wbase) * 8;      // wave-uniform LDS element base
      async_ld16(&A[(size_t)(m0+row)*K + k0 + c8], &lds_a[lbase]);
      async_ld16(&W[(size_t)(n0+row)*K + k0 + c8], &lds_w[lbase]);
    }
    __syncthreads();
    bf16x8 af[4], bfr[4];
    #pragma unroll
    for (int mt=0; mt<4; ++mt)
      af[mt] = *reinterpret_cast<const bf16x8*>(&lds_a[(wm*64 + mt*16 + lr)*32 + quad*8]);
    #pragma unroll
    for (int nt=0; nt<4; ++nt)
      bfr[nt] = *reinterpret_cast<const bf16x8*>(&lds_w[(wn*64 + nt*16 + lr)*32 + quad*8]);
    #pragma unroll
    for (int mt=0; mt<4; ++mt)
      #pragma unroll
      for (int nt=0; nt<4; ++nt)
        acc[mt][nt] = MFMA16(af[mt], bfr[nt], acc[mt][nt]);
  }

  if (MODE == 0) {
    float* O = reinterpret_cast<float*>(out);
    #pragma unroll
    for (int nt=0; nt<4; ++nt) {
      int n = n0 + wn*64 + nt*16 + lr;
      float bv = b0p[n];
      #pragma unroll
      for (int mt=0; mt<4; ++mt)
        #pragma unroll
        for (int r=0; r<4; ++r) {
          int m = m0 + wm*64 + mt*16 + quad*4 + r;
          O[(size_t)m * N + n] = acc[mt][nt][r] + bv;
        }
    }
  } else {
    int which = n0 >> 10;                    // block-uniform (128 | 1024)
    const float* bp = (which==0) ? b0p : (which==1) ? b1p : b2p;
    u16* dst = reinterpret_cast<u16*>(out) + (size_t)which * 4194304;
    if (which == 2) {
      // V^T: [(b*16+h)*64 + d]*2048 + s ; r -> consecutive s -> packed b64
      #pragma unroll
      for (int nt=0; nt<4; ++nt) {
        int nn = (n0 & 1023) + wn*64 + nt*16 + lr;
        float bv = bp[nn];
        int hh = nn >> 6, d = nn & 63;
        #pragma unroll
        for (int mt=0; mt<4; ++mt) {
          int m = m0 + wm*64 + mt*16 + quad*4;
          int b = m >> 11, s = m & 2047;
          u16 o[4];
          #pragma unroll
          for (int r=0; r<4; ++r) o[r] = f2bf(acc[mt][nt][r] + bv);
          *reinterpret_cast<uint2*>(&dst[((size_t)(b*16 + hh)*64 + d)*2048 + s]) =
              *reinterpret_cast<const uint2*>(o);
        }
      }
    } else {
      #pragma unroll
      for (int nt=0; nt<4; ++nt) {
        int nn = (n0 & 1023) + wn*64 + nt*16 + lr;
        float bv = bp[nn];
        int hh = nn >> 6, d = nn & 63;
        #pragma unroll
        for (int mt=0; mt<4; ++mt)
          #pragma unroll
          for (int r=0; r<4; ++r) {
            int m = m0 + wm*64 + mt*16 + quad*4 + r;
            int b = m >> 11, s = m & 2047;
            dst[((size_t)(b*16 + hh) * 2048 + s) * 64 + d] = f2bf(acc[mt][nt][r] + bv);
          }
      }
    }
  }
}

// In-place RMSNorm (over the 1024 pre-split channels) + RoPE on [B,H,S,D] bf16.
// blockIdx.y selects q (0) or k (1).
__global__ __launch_bounds__(256) void rmsrope(u16* __restrict__ qb, u16* __restrict__ kb,
                                               const float* __restrict__ cosb,
                                               const float* __restrict__ sinb,
                                               const float* __restrict__ w)
{
  u16* buf = blockIdx.y ? kb : qb;
  const int bs = blockIdx.x;
  const int b = bs >> 11, s = bs & 2047;
  const int t = threadIdx.x;
  float x1[2], x2[2];
  float ss = 0.f;
  #pragma unroll
  for (int i=0;i<2;++i){
    int p = t + i*256;            // 512 pairs cover 1024 channels
    int h = p >> 5, d = p & 31;
    size_t base = ((size_t)(b*16+h)*2048 + s)*64;
    x1[i] = bf2f(buf[base + d]);
    x2[i] = bf2f(buf[base + d + 32]);
    ss += x1[i]*x1[i] + x2[i]*x2[i];
  }
  #pragma unroll
  for (int off=32; off>0; off>>=1) ss += __shfl_xor(ss, off, 64);
  __shared__ float red[4];
  if ((t & 63) == 0) red[t>>6] = ss;
  __syncthreads();
  float tot = red[0]+red[1]+red[2]+red[3];
  float r = rsqrtf(tot * (1.0f/1024.0f) + 1e-6f);
  #pragma unroll
  for (int i=0;i<2;++i){
    int p = t + i*256;
    int h = p >> 5, d = p & 31;
    size_t base = ((size_t)(b*16+h)*2048 + s)*64;
    float w1 = w[h*64+d], w2 = w[h*64+d+32];
    float n1 = x1[i]*r*w1, n2 = x2[i]*r*w2;
    float c1 = cosb[s*64+d],    s1 = sinb[s*64+d];
    float c2 = cosb[s*64+d+32], s2 = sinb[s*64+d+32];
    buf[base+d]    = f2bf(n1*c1 - n2*s1);
    buf[base+d+32] = f2bf(n2*c2 + n1*s2);
  }
}

// Flash attention, transposed-score formulation (no P LDS round-trip):
//   S^T = K·Q^T  (A=K-frag, B=Q-frag) -> C-layout: lane holds P^T[key=q4+r][q=lr]
//   O^T = V^T·P^T (A=V^T-frag, B=packed P from two 16-key subtiles per K=32 MFMA)
// scores = QK^T/8 + (k<=q ? 1 : 0); softmax over all keys (bounded -> no max-tracking).
__global__ __launch_bounds__(256) void attn(const u16* __restrict__ qh,
                                            const u16* __restrict__ kh,
                                            const u16* __restrict__ vt,
                                            u16* __restrict__ ao)
{
  __shared__ __align__(16) u16 kbuf[64*64];     // [key][d], chunk pos = c ^ (key&7)
  __shared__ __align__(16) u16 vbuf[64*64];     // [d][key], chunk pos = c ^ (d&7)
  const int t = threadIdx.x;
  const int lane = t & 63, w = t >> 6;
  const int lr = lane & 15, quad = lane >> 4;
  const int qbase = blockIdx.x * 64;
  const int bh = blockIdx.y;
  const int b = bh >> 4, h = bh & 15;
  const size_t hb = (size_t)bh * 2048 * 64;
  const u16* qp = qh + hb;
  const u16* kp = kh + hb;
  const u16* vtp = vt + hb;

  const int q_abs = qbase + w*16 + lr;          // this lane's q row
  bf16x8 qf0 = *reinterpret_cast<const bf16x8*>(&qp[(size_t)q_abs*64 + quad*8]);
  bf16x8 qf1 = *reinterpret_cast<const bf16x8*>(&qp[(size_t)q_abs*64 + 32 + quad*8]);

  const f32x4 fzero = {0.f,0.f,0.f,0.f};
  f32x4 oacc[4];
  #pragma unroll
  for (int i=0;i<4;++i) oacc[i] = fzero;
  float lsum = 0.f;

  for (int kt=0; kt<32; ++kt) {
    __syncthreads();                            // kbuf/vbuf free (prev readers done)
    #pragma unroll
    for (int it=0; it<2; ++it) {
      int idx = it*256 + t;
      int row = idx >> 3, c = idx & 7;          // row: key (kbuf) / d (vbuf)
      uint4 kvv = *reinterpret_cast<const uint4*>(&kp[(size_t)(kt*64+row)*64 + c*8]);
      uint4 vvv = *reinterpret_cast<const uint4*>(&vtp[(size_t)row*2048 + kt*64 + c*8]);
      int sw = ((c ^ (row&7))&7)*8;
      *reinterpret_cast<uint4*>(&kbuf[row*64 + sw]) = kvv;
      *reinterpret_cast<uint4*>(&vbuf[row*64 + sw]) = vvv;
    }
    __syncthreads();

    // S^T + exp, packed into two K=32 B-fragments (keys 0-31 and 32-63)
    bf16x8 pfr[2];
    #pragma unroll
    for (int u=0; u<2; ++u) {
      bf16x4 ph[2];
      #pragma unroll
      for (int sidx=0; sidx<2; ++sidx) {
        int ksub = u*2 + sidx;
        int row = ksub*16 + lr, sw = row & 7;
        bf16x8 a0 = *reinterpret_cast<const bf16x8*>(&kbuf[row*64 + ((quad ^ sw)&7)*8]);
        bf16x8 a1 = *reinterpret_cast<const bf16x8*>(&kbuf[row*64 + ((quad ^ sw ^ 4)&7)*8]);
        f32x4 z = fzero;
        z = MFMA16(a0, qf0, z);                 // S^T = K · Q^T
        z = MFMA16(a1, qf1, z);
        int key0 = kt*64 + ksub*16 + quad*4;
        u16 pp[4];
        #pragma unroll
        for (int r=0; r<4; ++r) {
          float sc = z[r]*0.125f + ((key0 + r <= q_abs) ? 1.0f : 0.0f);
          float p = __expf(sc);
          lsum += p;
          pp[r] = f2bf(p);
        }
        __builtin_memcpy(&ph[sidx], pp, 8);
      }
      pfr[u] = __builtin_shufflevector(ph[0], ph[1], 0,1,2,3,4,5,6,7);
    }

    // O^T += V^T · P^T  (virtual-k: j<4 -> subtile 2u, j>=4 -> subtile 2u+1)
    #pragma unroll
    for (int u=0; u<2; ++u) {
      #pragma unroll
      for (int dt=0; dt<4; ++dt) {
        int row = dt*16 + lr, sw = row & 7;
        int c0 = u*4 + (quad>>1);               // chunk of e0 = u*32 + quad*4
        int io = (quad&1)*4;                    // in-chunk element offset
        bf16x4 v0, v1;
        __builtin_memcpy(&v0, &vbuf[row*64 + ((c0 ^ sw)&7)*8 + io], 8);
        __builtin_memcpy(&v1, &vbuf[row*64 + (((c0+2) ^ sw)&7)*8 + io], 8);
        bf16x8 vf = __builtin_shufflevector(v0, v1, 0,1,2,3,4,5,6,7);
        oacc[dt] = MFMA16(vf, pfr[u], oacc[dt]);
      }
    }
  }

  lsum += __shfl_xor(lsum, 16, 64);             // reduce across quads (same q=lr)
  lsum += __shfl_xor(lsum, 32, 64);
  float inv = 1.0f / lsum;
  size_t rowbase = ((size_t)(b*2048 + q_abs))*1024 + h*64;
  #pragma unroll
  for (int dt=0; dt<4; ++dt) {
    u16 o[4];
    #pragma unroll
    for (int r=0; r<4; ++r) o[r] = f2bf(oacc[dt][r] * inv);
    *reinterpret_cast<uint2*>(&ao[rowbase + dt*16 + quad*4]) =
        *reinterpret_cast<const uint2*>(o);
  }
}

extern "C" void kernel_launch(void* const* d_in, const int* in_sizes, int n_in,
                              void* d_out, int out_size, void* d_ws, size_t ws_size,
                              hipStream_t stream)
{
  const float* hs   = (const float*)d_in[0];
  const float* cosb = (const float*)d_in[1];
  const float* sinb = (const float*)d_in[2];
  const float* Wq   = (const float*)d_in[3];
  const float* bq   = (const float*)d_in[4];
  const float* Wk   = (const float*)d_in[5];
  const float* bk   = (const float*)d_in[6];
  const float* Wv   = (const float*)d_in[7];
  const float* bv   = (const float*)d_in[8];
  const float* Wo   = (const float*)d_in[9];
  const float* bo   = (const float*)d_in[10];
  const float* rw   = (const float*)d_in[11];

  const size_t NEL = (size_t)4096 * 1024;   // 4M
  const size_t WEL = (size_t)1024 * 1024;   // 1M
  u16* hsb = (u16*)d_ws;                    // bf16 hs [4096,1024]
  u16* wqb = hsb + NEL;                     // Wq,Wk,Wv contiguous (fused QKV GEMM)
  u16* wob = wqb + 3*WEL;
  u16* qhb = wob + WEL;                     // q,k head layout [B,H,S,D]; v -> V^T [B,H,D,S]
  u16* khb = qhb + NEL;
  u16* vtb = khb + NEL;                     // written transposed by gemm_k<1>
  u16* aob = hsb;                           // reuse: hs consumed by QKV GEMM

  cast_all<<<4096, 256, 0, stream>>>(hs, Wq, Wk, Wv, Wo, hsb);
  gemm_k<1><<<dim3(24,32), 256, 0, stream>>>(hsb, wqb, bq, bk, bv, qhb, 4096, 3072, 1024);
  rmsrope<<<dim3(4096,2), 256, 0, stream>>>(qhb, khb, cosb, sinb, rw);
  attn<<<dim3(32,32), 256, 0, stream>>>(qhb, khb, vtb, aob);
  gemm_k<0><<<dim3(8,32), 256, 0, stream>>>(aob, wob, bo, nullptr, nullptr, d_out, 4096, 1024, 1024);
}

// Round 7
// 235.224 us; speedup vs baseline: 1.4798x; 1.0630x over previous
//
#include <hip/hip_runtime.h>

typedef unsigned short u16;
typedef __attribute__((ext_vector_type(8))) short bf16x8;
typedef __attribute__((ext_vector_type(4))) float f32x4;

#define MFMA16(A,B,C) __builtin_amdgcn_mfma_f32_16x16x32_bf16(A,B,C,0,0,0)
#define LOG2E 1.4426950408889634f
#define C1 0.18033688011112042f   // 0.125 * log2(e)

__device__ __forceinline__ u16 f2bf(float f){
  unsigned int u; __builtin_memcpy(&u,&f,4);
  unsigned int r = (u + 0x7fffu + ((u>>16)&1u)) >> 16;   // RNE
  return (u16)r;
}
__device__ __forceinline__ float bf2f(u16 h){
  unsigned int u = ((unsigned int)h) << 16;
  float f; __builtin_memcpy(&f,&u,4); return f;
}
// pack two fp32 -> bf16 pair (RNE), low16 = a, high16 = b
__device__ __forceinline__ unsigned int pack_bf16(float a, float b){
  unsigned int ua, ub;
  __builtin_memcpy(&ua,&a,4); __builtin_memcpy(&ub,&b,4);
  ua = ua + 0x7fffu + ((ua>>16)&1u);
  ub = ub + 0x7fffu + ((ub>>16)&1u);
  return __builtin_amdgcn_perm(ub, ua, 0x07060302);      // {b.hi16, a.hi16}
}

// async global->LDS, 16B per lane; LDS dest = wave-uniform base + lane*16.
__device__ __forceinline__ void async_ld16(const void* g, void* l) {
  __builtin_amdgcn_global_load_lds(
      (const __attribute__((address_space(1))) unsigned int*)g,
      (__attribute__((address_space(3))) unsigned int*)l, 16, 0, 0);
}

// Cast hs (4M el) + Wq,Wk,Wv,Wo (1M each) fp32->bf16 into contiguous ws.
__global__ __launch_bounds__(256) void cast_all(const float* __restrict__ hs,
    const float* __restrict__ wq, const float* __restrict__ wk,
    const float* __restrict__ wv, const float* __restrict__ wo,
    u16* __restrict__ dst)
{
  unsigned int i = blockIdx.x*256 + threadIdx.x;     // chunk of 8 elements
  size_t el = (size_t)i * 8;
  const float* src; size_t off;
  if (el < 4194304) { src = hs; off = el; }
  else {
    unsigned int r = (unsigned int)((el - 4194304) >> 20);
    src = (r==0)?wq:(r==1)?wk:(r==2)?wv:wo;
    off = (el - 4194304) & 1048575;
  }
  float4 a = *reinterpret_cast<const float4*>(src+off);
  float4 b = *reinterpret_cast<const float4*>(src+off+4);
  u16 tmp[8] = {f2bf(a.x),f2bf(a.y),f2bf(a.z),f2bf(a.w),
                f2bf(b.x),f2bf(b.y),f2bf(b.z),f2bf(b.w)};
  *reinterpret_cast<uint4*>(dst + el) = *reinterpret_cast<const uint4*>(tmp);
}

// QKV GEMM: C = A[M,K] @ W[N,K]^T + bias, 128x128 tiles, async staging.
// which = n/1024 routes q/k -> head layout [bh][s][d]; v -> transposed [bh][d][s].
__global__ __launch_bounds__(256) void gemm_qkv(const u16* __restrict__ A,
                                                const u16* __restrict__ W,
                                                const float* __restrict__ b0p,
                                                const float* __restrict__ b1p,
                                                const float* __restrict__ b2p,
                                                u16* __restrict__ out,
                                                int M, int N, int K)
{
  __shared__ __align__(16) u16 lds_a[128*32];
  __shared__ __align__(16) u16 lds_w[128*32];
  const int t = threadIdx.x;
  const int lane = t & 63, wave = t >> 6;
  const int wm = wave >> 1, wn = wave & 1;
  const int lr = lane & 15, quad = lane >> 4;
  const int n0 = blockIdx.x * 128, m0 = blockIdx.y * 128;
  const int wbase = t & 192;

  const f32x4 fzero = {0.f,0.f,0.f,0.f};
  f32x4 acc[4][4];
  #pragma unroll
  for (int i=0;i<4;++i)
    #pragma unroll
    for (int j=0;j<4;++j) acc[i][j] = fzero;

  for (int k0 = 0; k0 < K; k0 += 32) {
    __syncthreads();
    #pragma unroll
    for (int it=0; it<2; ++it) {
      int idx = it*256 + t;
      int row = idx >> 2, c8 = (idx & 3) * 8;
      int lbase = (it*256 + wbase) * 8;
      async_ld16(&A[(size_t)(m0+row)*K + k0 + c8], &lds_a[lbase]);
      async_ld16(&W[(size_t)(n0+row)*K + k0 + c8], &lds_w[lbase]);
    }
    __syncthreads();
    bf16x8 af[4], bfr[4];
    #pragma unroll
    for (int mt=0; mt<4; ++mt)
      af[mt] = *reinterpret_cast<const bf16x8*>(&lds_a[(wm*64 + mt*16 + lr)*32 + quad*8]);
    #pragma unroll
    for (int nt=0; nt<4; ++nt)
      bfr[nt] = *reinterpret_cast<const bf16x8*>(&lds_w[(wn*64 + nt*16 + lr)*32 + quad*8]);
    #pragma unroll
    for (int mt=0; mt<4; ++mt)
      #pragma unroll
      for (int nt=0; nt<4; ++nt)
        acc[mt][nt] = MFMA16(af[mt], bfr[nt], acc[mt][nt]);
  }

  int which = n0 >> 10;
  const float* bp = (which==0) ? b0p : (which==1) ? b1p : b2p;
  u16* dst = out + (size_t)which * 4194304;
  if (which == 2) {
    // V^T: [(b*16+h)*64 + d]*2048 + s ; r -> consecutive s -> packed b64
    #pragma unroll
    for (int nt=0; nt<4; ++nt) {
      int nn = (n0 & 1023) + wn*64 + nt*16 + lr;
      float bv = bp[nn];
      int hh = nn >> 6, d = nn & 63;
      #pragma unroll
      for (int mt=0; mt<4; ++mt) {
        int m = m0 + wm*64 + mt*16 + quad*4;
        int b = m >> 11, s = m & 2047;
        u16 o[4];
        #pragma unroll
        for (int r=0; r<4; ++r) o[r] = f2bf(acc[mt][nt][r] + bv);
        *reinterpret_cast<uint2*>(&dst[((size_t)(b*16 + hh)*64 + d)*2048 + s]) =
            *reinterpret_cast<const uint2*>(o);
      }
    }
  } else {
    #pragma unroll
    for (int nt=0; nt<4; ++nt) {
      int nn = (n0 & 1023) + wn*64 + nt*16 + lr;
      float bv = bp[nn];
      int hh = nn >> 6, d = nn & 63;
      #pragma unroll
      for (int mt=0; mt<4; ++mt)
        #pragma unroll
        for (int r=0; r<4; ++r) {
          int m = m0 + wm*64 + mt*16 + quad*4 + r;
          int b = m >> 11, s = m & 2047;
          dst[((size_t)(b*16 + hh) * 2048 + s) * 64 + d] = f2bf(acc[mt][nt][r] + bv);
        }
    }
  }
}

// Out-proj GEMM: 128M x 64N tiles (512 blocks -> 2/CU), fp32 out.
__global__ __launch_bounds__(256) void gemm_o(const u16* __restrict__ A,
                                              const u16* __restrict__ W,
                                              const float* __restrict__ bias,
                                              float* __restrict__ O,
                                              int M, int N, int K)
{
  __shared__ __align__(16) u16 lds_a[128*32];
  __shared__ __align__(16) u16 lds_w[64*32];
  const int t = threadIdx.x;
  const int lane = t & 63, wm = t >> 6;      // wave owns 32 M-rows
  const int lr = lane & 15, quad = lane >> 4;
  const int n0 = blockIdx.x * 64, m0 = blockIdx.y * 128;
  const int wbase = t & 192;

  const f32x4 fzero = {0.f,0.f,0.f,0.f};
  f32x4 acc[2][4];
  #pragma unroll
  for (int i=0;i<2;++i)
    #pragma unroll
    for (int j=0;j<4;++j) acc[i][j] = fzero;

  for (int k0 = 0; k0 < K; k0 += 32) {
    __syncthreads();
    #pragma unroll
    for (int it=0; it<2; ++it) {
      int idx = it*256 + t;
      int row = idx >> 2, c8 = (idx & 3) * 8;
      int lbase = (it*256 + wbase) * 8;
      async_ld16(&A[(size_t)(m0+row)*K + k0 + c8], &lds_a[lbase]);
    }
    async_ld16(&W[(size_t)(n0 + (t>>2))*K + k0 + (t&3)*8], &lds_w[wbase*8]);
    __syncthreads();
    bf16x8 af[2], bfr[4];
    #pragma unroll
    for (int mt=0; mt<2; ++mt)
      af[mt] = *reinterpret_cast<const bf16x8*>(&lds_a[(wm*32 + mt*16 + lr)*32 + quad*8]);
    #pragma unroll
    for (int nt=0; nt<4; ++nt)
      bfr[nt] = *reinterpret_cast<const bf16x8*>(&lds_w[(nt*16 + lr)*32 + quad*8]);
    #pragma unroll
    for (int mt=0; mt<2; ++mt)
      #pragma unroll
      for (int nt=0; nt<4; ++nt)
        acc[mt][nt] = MFMA16(af[mt], bfr[nt], acc[mt][nt]);
  }

  #pragma unroll
  for (int nt=0; nt<4; ++nt) {
    int n = n0 + nt*16 + lr;
    float bv = bias[n];
    #pragma unroll
    for (int mt=0; mt<2; ++mt)
      #pragma unroll
      for (int r=0; r<4; ++r) {
        int m = m0 + wm*32 + mt*16 + quad*4 + r;
        O[(size_t)m * N + n] = acc[mt][nt][r] + bv;
      }
  }
}

// In-place RMSNorm (over the 1024 pre-split channels) + RoPE on [B,H,S,D] bf16.
__global__ __launch_bounds__(256) void rmsrope(u16* __restrict__ qb, u16* __restrict__ kb,
                                               const float* __restrict__ cosb,
                                               const float* __restrict__ sinb,
                                               const float* __restrict__ w)
{
  u16* buf = blockIdx.y ? kb : qb;
  const int bs = blockIdx.x;
  const int b = bs >> 11, s = bs & 2047;
  const int t = threadIdx.x;
  float x1[2], x2[2];
  float ss = 0.f;
  #pragma unroll
  for (int i=0;i<2;++i){
    int p = t + i*256;
    int h = p >> 5, d = p & 31;
    size_t base = ((size_t)(b*16+h)*2048 + s)*64;
    x1[i] = bf2f(buf[base + d]);
    x2[i] = bf2f(buf[base + d + 32]);
    ss += x1[i]*x1[i] + x2[i]*x2[i];
  }
  #pragma unroll
  for (int off=32; off>0; off>>=1) ss += __shfl_xor(ss, off, 64);
  __shared__ float red[4];
  if ((t & 63) == 0) red[t>>6] = ss;
  __syncthreads();
  float tot = red[0]+red[1]+red[2]+red[3];
  float r = rsqrtf(tot * (1.0f/1024.0f) + 1e-6f);
  #pragma unroll
  for (int i=0;i<2;++i){
    int p = t + i*256;
    int h = p >> 5, d = p & 31;
    size_t base = ((size_t)(b*16+h)*2048 + s)*64;
    float w1 = w[h*64+d], w2 = w[h*64+d+32];
    float n1 = x1[i]*r*w1, n2 = x2[i]*r*w2;
    float c1 = cosb[s*64+d],    s1 = sinb[s*64+d];
    float c2 = cosb[s*64+d+32], s2 = sinb[s*64+d+32];
    buf[base+d]    = f2bf(n1*c1 - n2*s1);
    buf[base+d+32] = f2bf(n2*c2 + n1*s2);
  }
}

// Flash attention, transposed-score formulation.
//   S^T = K·Q^T  -> C-layout: lane holds P^T[key=ksub*16+quad*4+r][q=lr]
//   O^T = V^T·P^T with vbuf stored in virtual-k order -> direct b128 A-frags.
// Causal mask block-uniform except the diagonal tile (kt == blockIdx.x).
__global__ __launch_bounds__(256) void attn(const u16* __restrict__ qh,
                                            const u16* __restrict__ kh,
                                            const u16* __restrict__ vt,
                                            u16* __restrict__ ao)
{
  __shared__ __align__(16) u16 kbuf[64*72];     // [key][d], pad 72, no swizzle
  __shared__ __align__(16) u16 vbuf[64*72];     // [d][virtual-k], pad 72
  const int t = threadIdx.x;
  const int lane = t & 63, w = t >> 6;
  const int lr = lane & 15, quad = lane >> 4;
  const int bx = blockIdx.x;
  const int qbase = bx * 64;
  const int bh = blockIdx.y;
  const int b = bh >> 4, h = bh & 15;
  const size_t hb = (size_t)bh * 2048 * 64;
  const u16* qp = qh + hb;
  const u16* kp = kh + hb;
  const u16* vtp = vt + hb;

  const int q_abs = qbase + w*16 + lr;
  bf16x8 qf0 = *reinterpret_cast<const bf16x8*>(&qp[(size_t)q_abs*64 + quad*8]);
  bf16x8 qf1 = *reinterpret_cast<const bf16x8*>(&qp[(size_t)q_abs*64 + 32 + quad*8]);

  // staging constants: thread owns chunk cc of rows row0 and row0+32
  const int row0 = t >> 3;                      // 0..31
  const int cc = t & 7;
  const int c8 = cc * 8;
  const int P0 = ((cc>>2)*32) + ((cc&1)*16) + (((cc>>1)&1)*4);  // virtual-k base
  u16* kw0 = &kbuf[row0*72 + c8];
  u16* kw1 = &kbuf[(row0+32)*72 + c8];
  u16* vw0 = &vbuf[row0*72 + P0];
  u16* vw1 = &vbuf[(row0+32)*72 + P0];

  const f32x4 fzero = {0.f,0.f,0.f,0.f};
  f32x4 oacc[4];
  #pragma unroll
  for (int i=0;i<4;++i) oacc[i] = fzero;
  float lsum = 0.f;
  const int qoff = w*16 + lr;

  for (int kt=0; kt<32; ++kt) {
    __syncthreads();
    {
      const u16* kg = kp + (size_t)kt*4096 + row0*64 + c8;
      const u16* vg = vtp + (size_t)row0*2048 + kt*64 + c8;
      uint4 k0 = *reinterpret_cast<const uint4*>(kg);
      uint4 k1 = *reinterpret_cast<const uint4*>(kg + 32*64);
      uint4 v0 = *reinterpret_cast<const uint4*>(vg);
      uint4 v1 = *reinterpret_cast<const uint4*>(vg + 32*2048);
      *reinterpret_cast<uint4*>(kw0) = k0;
      *reinterpret_cast<uint4*>(kw1) = k1;
      uint2 a0 = {v0.x, v0.y}, a1 = {v0.z, v0.w};
      uint2 b0 = {v1.x, v1.y}, b1 = {v1.z, v1.w};
      *reinterpret_cast<uint2*>(vw0)     = a0;
      *reinterpret_cast<uint2*>(vw0 + 8) = a1;
      *reinterpret_cast<uint2*>(vw1)     = b0;
      *reinterpret_cast<uint2*>(vw1 + 8) = b1;
    }
    __syncthreads();

    // S^T = K · Q^T
    f32x4 zz[4];
    #pragma unroll
    for (int ksub=0; ksub<4; ++ksub) {
      const u16* kr = &kbuf[(ksub*16+lr)*72 + quad*8];
      bf16x8 a0, a1;
      __builtin_memcpy(&a0, kr, 16);
      __builtin_memcpy(&a1, kr+32, 16);
      f32x4 z = fzero;
      z = MFMA16(a0, qf0, z);
      z = MFMA16(a1, qf1, z);
      zz[ksub] = z;
    }

    // P = exp(S/8 + mask); mask block-uniform except diagonal tile
    unsigned int pk[4][2];
    if (kt != bx) {
      float ml = (kt < bx) ? LOG2E : 0.0f;
      #pragma unroll
      for (int ksub=0; ksub<4; ++ksub) {
        float p0 = __builtin_amdgcn_exp2f(__builtin_fmaf(zz[ksub][0], C1, ml));
        float p1 = __builtin_amdgcn_exp2f(__builtin_fmaf(zz[ksub][1], C1, ml));
        float p2 = __builtin_amdgcn_exp2f(__builtin_fmaf(zz[ksub][2], C1, ml));
        float p3 = __builtin_amdgcn_exp2f(__builtin_fmaf(zz[ksub][3], C1, ml));
        lsum += (p0+p1) + (p2+p3);
        pk[ksub][0] = pack_bf16(p0, p1);
        pk[ksub][1] = pack_bf16(p2, p3);
      }
    } else {
      #pragma unroll
      for (int ksub=0; ksub<4; ++ksub) {
        int koff = ksub*16 + quad*4;
        float p[4];
        #pragma unroll
        for (int r=0; r<4; ++r) {
          float ml = (koff + r <= qoff) ? LOG2E : 0.0f;
          p[r] = __builtin_amdgcn_exp2f(__builtin_fmaf(zz[ksub][r], C1, ml));
          lsum += p[r];
        }
        pk[ksub][0] = pack_bf16(p[0], p[1]);
        pk[ksub][1] = pack_bf16(p[2], p[3]);
      }
    }

    // O^T += V^T · P^T  (vbuf rows already in virtual-k order)
    #pragma unroll
    for (int u=0; u<2; ++u) {
      uint4 pq = {pk[2*u][0], pk[2*u][1], pk[2*u+1][0], pk[2*u+1][1]};
      bf16x8 pf;
      __builtin_memcpy(&pf, &pq, 16);
      #pragma unroll
      for (int dt=0; dt<4; ++dt) {
        bf16x8 vf;
        __builtin_memcpy(&vf, &vbuf[(dt*16+lr)*72 + u*32 + quad*8], 16);
        oacc[dt] = MFMA16(vf, pf, oacc[dt]);
      }
    }
  }

  lsum += __shfl_xor(lsum, 16, 64);
  lsum += __shfl_xor(lsum, 32, 64);
  float inv = 1.0f / lsum;
  size_t rowbase = ((size_t)(b*2048 + q_abs))*1024 + h*64;
  #pragma unroll
  for (int dt=0; dt<4; ++dt) {
    u16 o[4];
    #pragma unroll
    for (int r=0; r<4; ++r) o[r] = f2bf(oacc[dt][r] * inv);
    *reinterpret_cast<uint2*>(&ao[rowbase + dt*16 + quad*4]) =
        *reinterpret_cast<const uint2*>(o);
  }
}

extern "C" void kernel_launch(void* const* d_in, const int* in_sizes, int n_in,
                              void* d_out, int out_size, void* d_ws, size_t ws_size,
                              hipStream_t stream)
{
  const float* hs   = (const float*)d_in[0];
  const float* cosb = (const float*)d_in[1];
  const float* sinb = (const float*)d_in[2];
  const float* Wq   = (const float*)d_in[3];
  const float* bq   = (const float*)d_in[4];
  const float* Wk   = (const float*)d_in[5];
  const float* bk   = (const float*)d_in[6];
  const float* Wv   = (const float*)d_in[7];
  const float* bv   = (const float*)d_in[8];
  const float* Wo   = (const float*)d_in[9];
  const float* bo   = (const float*)d_in[10];
  const float* rw   = (const float*)d_in[11];

  const size_t NEL = (size_t)4096 * 1024;   // 4M
  const size_t WEL = (size_t)1024 * 1024;   // 1M
  u16* hsb = (u16*)d_ws;                    // bf16 hs [4096,1024]
  u16* wqb = hsb + NEL;                     // Wq,Wk,Wv contiguous (fused QKV GEMM)
  u16* wob = wqb + 3*WEL;
  u16* qhb = wob + WEL;                     // q,k head layout; v -> V^T [bh][d][s]
  u16* khb = qhb + NEL;
  u16* vtb = khb + NEL;
  u16* aob = hsb;                           // reuse: hs consumed by QKV GEMM

  cast_all<<<4096, 256, 0, stream>>>(hs, Wq, Wk, Wv, Wo, hsb);
  gemm_qkv<<<dim3(24,32), 256, 0, stream>>>(hsb, wqb, bq, bk, bv, qhb, 4096, 3072, 1024);
  rmsrope<<<dim3(4096,2), 256, 0, stream>>>(qhb, khb, cosb, sinb, rw);
  attn<<<dim3(32,32), 256, 0, stream>>>(qhb, khb, vtb, aob);
  gemm_o<<<dim3(16,32), 256, 0, stream>>>(aob, wob, bo, (float*)d_out, 4096, 1024, 1024);
}